// Round 1
// baseline (2830.183 us; speedup 1.0000x reference)
//
#include <hip/hip_runtime.h>
#include <math.h>

#define HH 128
#define HP 64   // u32 pairs per 128-feature row

// ---------- helpers ----------
__device__ __forceinline__ float blo(unsigned w){ return __uint_as_float(w << 16); }
__device__ __forceinline__ float bhi(unsigned w){ return __uint_as_float(w & 0xffff0000u); }
__device__ __forceinline__ unsigned short f2b(float x){
  unsigned u = __float_as_uint(x);
  u += 0x7fffu + ((u >> 16) & 1u);           // RNE to bf16
  return (unsigned short)(u >> 16);
}
__device__ __forceinline__ unsigned pack2(float a, float b){
  return (unsigned)f2b(a) | ((unsigned)f2b(b) << 16);
}
__device__ __forceinline__ float silu_f(float x){ return x / (1.f + __expf(-x)); }

// ---------- 1) per-node precompute: A = h@W[0:128] + bias, B = h@W[128:256] ----------
__global__ __launch_bounds__(256) void precompute_kernel(
    const float* __restrict__ h, const float* __restrict__ W,
    const float* __restrict__ bias,
    unsigned* __restrict__ Aout, unsigned* __restrict__ Bout, int N)
{
  __shared__ unsigned Wl[256 * HP];           // 64 KB, rows 0..255 packed bf16
  int t = threadIdx.x;
  const float2* W2 = (const float2*)W;
  for (int i = t; i < 256 * HP; i += 256) {
    float2 w = W2[i];
    Wl[i] = pack2(w.x, w.y);
  }
  __syncthreads();

  int wid = blockIdx.x * 4 + (t >> 6);
  int nw  = gridDim.x * 4;
  int jp  = t & 63;
  for (int n = wid; n < N; n += nw) {
    const float4* hn = (const float4*)(h + (size_t)n * HH);
    float a0 = 0.f, a1 = 0.f, b0 = 0.f, b1 = 0.f;
    #pragma unroll 8
    for (int k4 = 0; k4 < 32; ++k4) {
      float4 hv = hn[k4];                     // wave-uniform broadcast load
      float xs[4] = {hv.x, hv.y, hv.z, hv.w};
      #pragma unroll
      for (int u = 0; u < 4; ++u) {
        int k = 4 * k4 + u;
        unsigned wa = Wl[k * HP + jp];
        unsigned wb = Wl[(128 + k) * HP + jp];
        a0 += xs[u] * blo(wa); a1 += xs[u] * bhi(wa);
        b0 += xs[u] * blo(wb); b1 += xs[u] * bhi(wb);
      }
    }
    a0 += bias[2 * jp]; a1 += bias[2 * jp + 1];
    Aout[(size_t)n * HP + jp] = pack2(a0, a1);
    Bout[(size_t)n * HP + jp] = pack2(b0, b1);
  }
}

// ---------- 2) edge kernels: MODE 0 = edge MLP (att -> h_agg), MODE 1 = coord MLP (-> x_agg) ----------
template<int MODE>
__global__ __launch_bounds__(256) void edge_kernel(
    const unsigned* __restrict__ Apart, const unsigned* __restrict__ Bpart,
    const float* __restrict__ W1,       // (276,128), tail rows 256..275 used here
    const float* __restrict__ W2, const float* __restrict__ b2,
    const float* __restrict__ Wv,       // Wa (mode0) or Wc3 (mode1)
    const float* __restrict__ ba_p,     // ba (mode0), unused mode1
    const int* __restrict__ src, const int* __restrict__ dst,
    const float* __restrict__ coords, const float* __restrict__ afeat,
    float* __restrict__ out_agg, int E)
{
  __shared__ unsigned W2l[128 * HP];          // 32 KB bf16 layer-2 weights
  __shared__ float    Wtl[20 * 128];          // 10 KB f32 layer-1 tail (rows 256..275)
  __shared__ float    Wvl[128];
  __shared__ float    b2l[128];
  __shared__ float    mh[8][128];             // post-silu layer-1, 8 edges
  __shared__ float    dif[8][4];              // dx,dy,dz,rad
  __shared__ float    al[8][16];
  __shared__ int      sl[8], dl[8];

  int t = threadIdx.x;
  const float2* W2p = (const float2*)W2;
  for (int i = t; i < 128 * HP; i += 256) { float2 w = W2p[i]; W2l[i] = pack2(w.x, w.y); }
  for (int i = t; i < 20 * 128; i += 256) Wtl[i] = W1[256 * 128 + i];
  if (t < 128) { Wvl[t] = Wv[t]; b2l[t] = b2[t]; }
  float bav = (MODE == 0) ? ba_p[0] : 0.f;
  __syncthreads();

  int ntiles = (E + 7) >> 3;
  for (int tile = blockIdx.x; tile < ntiles; tile += gridDim.x) {
    int e0 = tile * 8;
    // ---- phase 0: stage per-edge scalars ----
    if (t < 8) {
      int eg = e0 + t;
      int s = 0, d = 0;
      if (eg < E) { s = src[eg]; d = dst[eg]; }
      sl[t] = s; dl[t] = d;
      float dx = coords[s*3+0] - coords[d*3+0];
      float dy = coords[s*3+1] - coords[d*3+1];
      float dz = coords[s*3+2] - coords[d*3+2];
      dif[t][0] = dx; dif[t][1] = dy; dif[t][2] = dz;
      dif[t][3] = sqrtf(dx*dx + dy*dy + dz*dz);
    }
    if (t >= 128) {
      int i = t - 128;                        // 0..127 = 8 edges x 16 feats
      int eg = e0 + (i >> 4);
      al[i >> 4][i & 15] = (eg < E) ? afeat[(size_t)eg * 16 + (i & 15)] : 0.f;
    }
    __syncthreads();

    // ---- phase A: layer 1 (gathered partials + 20-dim tail), silu -> mh ----
    #pragma unroll
    for (int r = 0; r < 2; ++r) {
      int q = r * 256 + t;
      int e = q >> 6, jp = q & 63;
      int s = sl[e], d = dl[e];
      unsigned wa = Apart[(size_t)s * HP + jp];
      unsigned wb = Bpart[(size_t)d * HP + jp];
      float t0 = blo(wa) + blo(wb);
      float t1 = bhi(wa) + bhi(wb);
      float De[4] = {dif[e][3], fabsf(dif[e][0]), fabsf(dif[e][1]), fabsf(dif[e][2])};
      #pragma unroll
      for (int k = 0; k < 4; ++k) {
        t0 += De[k] * Wtl[k * 128 + 2*jp];
        t1 += De[k] * Wtl[k * 128 + 2*jp + 1];
      }
      #pragma unroll
      for (int k = 0; k < 16; ++k) {
        float av = al[e][k];
        t0 += av * Wtl[(4 + k) * 128 + 2*jp];
        t1 += av * Wtl[(4 + k) * 128 + 2*jp + 1];
      }
      float2* me = (float2*)mh[e];
      me[jp] = make_float2(silu_f(t0), silu_f(t1));
    }
    __syncthreads();

    // ---- phase B: layer 2 + head + scatter ----
    #pragma unroll
    for (int r = 0; r < 2; ++r) {
      int q = r * 256 + t;
      int e = q >> 6, jp = q & 63;           // all 64 lanes of a wave share e
      float acc0 = b2l[2*jp], acc1 = b2l[2*jp + 1];
      const float2* me = (const float2*)mh[e];
      #pragma unroll 8
      for (int kk = 0; kk < 64; ++kk) {
        float2 m = me[kk];                    // broadcast
        unsigned w0 = W2l[(2*kk)     * HP + jp];
        unsigned w1 = W2l[(2*kk + 1) * HP + jp];
        acc0 += m.x * blo(w0) + m.y * blo(w1);
        acc1 += m.x * bhi(w0) + m.y * bhi(w1);
      }
      float v0 = silu_f(acc0), v1 = silu_f(acc1);
      float p = v0 * Wvl[2*jp] + v1 * Wvl[2*jp + 1];
      #pragma unroll
      for (int o = 32; o > 0; o >>= 1) p += __shfl_xor(p, o, 64);
      int eg = e0 + e;
      if (MODE == 0) {
        float att = 1.f / (1.f + __expf(-(p + bav)));
        if (eg < E) {
          int d = dl[e];
          unsafeAtomicAdd(&out_agg[(size_t)d * HH + 2*jp],     att * v0);
          unsafeAtomicAdd(&out_agg[(size_t)d * HH + 2*jp + 1], att * v1);
        }
      } else {
        if (eg < E && jp < 3) {
          float fac = p / (dif[e][3] + 1.f);
          unsafeAtomicAdd(&out_agg[(size_t)dl[e] * 3 + jp], fac * dif[e][jp]);
        }
      }
    }
    __syncthreads();                          // mh/sl/dl reused next tile
  }
}

// ---------- 3) node MLP layer 1: g = silu([h, h_agg] @ Wn1 + bn1), bf16-packed ----------
__global__ __launch_bounds__(256) void node_l1_kernel(
    const float* __restrict__ h, const float* __restrict__ h_agg,
    const float* __restrict__ Wn1, const float* __restrict__ bn1,
    unsigned* __restrict__ g, int N)
{
  __shared__ unsigned Wl[256 * HP];           // 64 KB
  int t = threadIdx.x;
  const float2* W2 = (const float2*)Wn1;
  for (int i = t; i < 256 * HP; i += 256) { float2 w = W2[i]; Wl[i] = pack2(w.x, w.y); }
  __syncthreads();

  int wid = blockIdx.x * 4 + (t >> 6);
  int nw  = gridDim.x * 4;
  int jp  = t & 63;
  for (int n = wid; n < N; n += nw) {
    float a0 = bn1[2*jp], a1 = bn1[2*jp + 1];
    const float4* hn = (const float4*)(h + (size_t)n * HH);
    const float4* gn = (const float4*)(h_agg + (size_t)n * HH);
    #pragma unroll 4
    for (int k4 = 0; k4 < 32; ++k4) {
      float4 hv = hn[k4];
      float xs[4] = {hv.x, hv.y, hv.z, hv.w};
      #pragma unroll
      for (int u = 0; u < 4; ++u) {
        unsigned w = Wl[(4*k4 + u) * HP + jp];
        a0 += xs[u] * blo(w); a1 += xs[u] * bhi(w);
      }
    }
    #pragma unroll 4
    for (int k4 = 0; k4 < 32; ++k4) {
      float4 hv = gn[k4];
      float xs[4] = {hv.x, hv.y, hv.z, hv.w};
      #pragma unroll
      for (int u = 0; u < 4; ++u) {
        unsigned w = Wl[(128 + 4*k4 + u) * HP + jp];
        a0 += xs[u] * blo(w); a1 += xs[u] * bhi(w);
      }
    }
    g[(size_t)n * HP + jp] = pack2(silu_f(a0), silu_f(a1));
  }
}

// ---------- 4) node MLP layer 2: h_out = h + g @ Wn2 + bn2 ----------
__global__ __launch_bounds__(256) void node_l2_kernel(
    const unsigned* __restrict__ g, const float* __restrict__ h,
    const float* __restrict__ Wn2, const float* __restrict__ bn2,
    float* __restrict__ hout, int N)
{
  __shared__ unsigned Wl[128 * HP];           // 32 KB
  int t = threadIdx.x;
  const float2* W2 = (const float2*)Wn2;
  for (int i = t; i < 128 * HP; i += 256) { float2 w = W2[i]; Wl[i] = pack2(w.x, w.y); }
  __syncthreads();

  int wid = blockIdx.x * 4 + (t >> 6);
  int nw  = gridDim.x * 4;
  int jp  = t & 63;
  for (int n = wid; n < N; n += nw) {
    float a0 = bn2[2*jp], a1 = bn2[2*jp + 1];
    const uint2* gn = (const uint2*)(g + (size_t)n * HP);
    #pragma unroll 4
    for (int k2 = 0; k2 < 32; ++k2) {
      uint2 gp = gn[k2];                      // 4 bf16 inputs (k = 4*k2 .. 4*k2+3)
      float x0 = blo(gp.x), x1 = bhi(gp.x), x2 = blo(gp.y), x3 = bhi(gp.y);
      unsigned w0 = Wl[(4*k2    ) * HP + jp];
      unsigned w1 = Wl[(4*k2 + 1) * HP + jp];
      unsigned w2 = Wl[(4*k2 + 2) * HP + jp];
      unsigned w3 = Wl[(4*k2 + 3) * HP + jp];
      a0 += x0*blo(w0) + x1*blo(w1) + x2*blo(w2) + x3*blo(w3);
      a1 += x0*bhi(w0) + x1*bhi(w1) + x2*bhi(w2) + x3*bhi(w3);
    }
    float2 hv = ((const float2*)h)[(size_t)n * HP + jp];
    ((float2*)hout)[(size_t)n * HP + jp] = make_float2(hv.x + a0, hv.y + a1);
  }
}

// ---------- 5) coords_out = coords + x_agg ----------
__global__ void coords_out_kernel(const float* __restrict__ coords,
                                  const float* __restrict__ x_agg,
                                  float* __restrict__ out, int n3)
{
  int i = blockIdx.x * blockDim.x + threadIdx.x;
  if (i < n3) out[i] = coords[i] + x_agg[i];
}

extern "C" void kernel_launch(void* const* d_in, const int* in_sizes, int n_in,
                              void* d_out, int out_size, void* d_ws, size_t ws_size,
                              hipStream_t stream)
{
  const float* h      = (const float*)d_in[0];
  const float* coords = (const float*)d_in[1];
  const float* afeat  = (const float*)d_in[2];
  const int*   src    = (const int*)d_in[3];
  const int*   dst    = (const int*)d_in[4];
  const float* We1 = (const float*)d_in[5];
  const float* be1 = (const float*)d_in[6];
  const float* We2 = (const float*)d_in[7];
  const float* be2 = (const float*)d_in[8];
  const float* Wa  = (const float*)d_in[9];
  const float* ba  = (const float*)d_in[10];
  const float* Wn1 = (const float*)d_in[11];
  const float* bn1 = (const float*)d_in[12];
  const float* Wn2 = (const float*)d_in[13];
  const float* bn2 = (const float*)d_in[14];
  const float* Wc1 = (const float*)d_in[15];
  const float* bc1 = (const float*)d_in[16];
  const float* Wc2 = (const float*)d_in[17];
  const float* bc2 = (const float*)d_in[18];
  const float* Wc3 = (const float*)d_in[19];

  const int E = in_sizes[3];
  const int N = in_sizes[0] / HH;

  // workspace layout (bf16-packed u32 partials, then f32 aggregators)
  unsigned* A1 = (unsigned*)d_ws;
  unsigned* B1 = A1 + (size_t)N * HP;
  unsigned* Ac = B1 + (size_t)N * HP;
  unsigned* Bc = Ac + (size_t)N * HP;
  float* h_agg = (float*)(Bc + (size_t)N * HP);
  float* x_agg = h_agg + (size_t)N * HH;
  unsigned* gbuf = A1;                        // reuse after edge kernels finish

  hipMemsetAsync(h_agg, 0, ((size_t)N * HH + (size_t)N * 3) * sizeof(float), stream);

  precompute_kernel<<<512, 256, 0, stream>>>(h, We1, be1, A1, B1, N);
  precompute_kernel<<<512, 256, 0, stream>>>(h, Wc1, bc1, Ac, Bc, N);

  edge_kernel<0><<<768, 256, 0, stream>>>(A1, B1, We1, We2, be2, Wa, ba,
                                          src, dst, coords, afeat, h_agg, E);
  edge_kernel<1><<<768, 256, 0, stream>>>(Ac, Bc, Wc1, Wc2, bc2, Wc3, nullptr,
                                          src, dst, coords, afeat, x_agg, E);

  node_l1_kernel<<<512, 256, 0, stream>>>(h, h_agg, Wn1, bn1, gbuf, N);
  node_l2_kernel<<<1024, 256, 0, stream>>>(gbuf, h, Wn2, bn2, (float*)d_out, N);
  coords_out_kernel<<<(N * 3 + 255) / 256, 256, 0, stream>>>(
      coords, x_agg, (float*)d_out + (size_t)N * HH, N * 3);
}

// Round 2
// 1177.670 us; speedup vs baseline: 2.4032x; 2.4032x over previous
//
#include <hip/hip_runtime.h>
#include <math.h>

#define HH 128
#define HP 64   // u32 pairs per 128-feature row

typedef __attribute__((ext_vector_type(8))) short short8;
typedef __attribute__((ext_vector_type(4))) float float4v;
typedef __attribute__((ext_vector_type(4))) unsigned uint4v;

// ---------- helpers ----------
__device__ __forceinline__ float blo(unsigned w){ return __uint_as_float(w << 16); }
__device__ __forceinline__ float bhi(unsigned w){ return __uint_as_float(w & 0xffff0000u); }
__device__ __forceinline__ unsigned short f2b(float x){
  unsigned u = __float_as_uint(x);
  u += 0x7fffu + ((u >> 16) & 1u);           // RNE to bf16
  return (unsigned short)(u >> 16);
}
__device__ __forceinline__ unsigned pack2(float a, float b){
  return (unsigned)f2b(a) | ((unsigned)f2b(b) << 16);
}
__device__ __forceinline__ float silu_f(float x){ return x / (1.f + __expf(-x)); }

// ---------- 1) per-node precompute: A = h@W[0:128] + bias, B = h@W[128:256] ----------
__global__ __launch_bounds__(256) void precompute_kernel(
    const float* __restrict__ h, const float* __restrict__ W,
    const float* __restrict__ bias,
    unsigned* __restrict__ Aout, unsigned* __restrict__ Bout, int N)
{
  __shared__ unsigned Wl[256 * HP];           // 64 KB, rows 0..255 packed bf16
  int t = threadIdx.x;
  const float2* W2 = (const float2*)W;
  for (int i = t; i < 256 * HP; i += 256) {
    float2 w = W2[i];
    Wl[i] = pack2(w.x, w.y);
  }
  __syncthreads();

  int wid = blockIdx.x * 4 + (t >> 6);
  int nw  = gridDim.x * 4;
  int jp  = t & 63;
  for (int n = wid; n < N; n += nw) {
    const float4* hn = (const float4*)(h + (size_t)n * HH);
    float a0 = 0.f, a1 = 0.f, b0 = 0.f, b1 = 0.f;
    #pragma unroll 8
    for (int k4 = 0; k4 < 32; ++k4) {
      float4 hv = hn[k4];                     // wave-uniform broadcast load
      float xs[4] = {hv.x, hv.y, hv.z, hv.w};
      #pragma unroll
      for (int u = 0; u < 4; ++u) {
        int k = 4 * k4 + u;
        unsigned wa = Wl[k * HP + jp];
        unsigned wb = Wl[(128 + k) * HP + jp];
        a0 += xs[u] * blo(wa); a1 += xs[u] * bhi(wa);
        b0 += xs[u] * blo(wb); b1 += xs[u] * bhi(wb);
      }
    }
    a0 += bias[2 * jp]; a1 += bias[2 * jp + 1];
    Aout[(size_t)n * HP + jp] = pack2(a0, a1);
    Bout[(size_t)n * HP + jp] = pack2(b0, b1);
  }
}

// ---------- 2) MFMA edge kernels: MODE 0 = edge MLP (att -> h_agg), MODE 1 = coord MLP (-> x_agg) ----------
// Tile = 32 edges. 4 waves: wave w handles Mtile=(w>>1) (16 edges), N-half=(w&1) (64 outs).
template<int MODE>
__global__ __launch_bounds__(256, 3) void edge_kernel(
    const unsigned* __restrict__ Apart, const unsigned* __restrict__ Bpart,
    const float* __restrict__ W1,       // (276,128); rows 256..275 = tail
    const float* __restrict__ W2, const float* __restrict__ b2,
    const float* __restrict__ Wv,       // Wa (mode0) or Wc3 (mode1), [128]
    const float* __restrict__ ba_p,     // ba (mode0), unused mode1
    const int* __restrict__ src, const int* __restrict__ dst,
    const float* __restrict__ coords, const float* __restrict__ afeat,
    float* __restrict__ out_agg, int E)
{
  // stride 68 u32 (=136 u16) pads rows by 4 u32 -> fragment b128 reads are 2-way (free)
  __shared__ unsigned short W2Ts[128 * 136];  // 34 KB bf16, n-major: W2T[n][k]
  __shared__ unsigned mhl[32 * 68];           // 8.7 KB bf16-pairs, mh[e][k/2]
  __shared__ float    tails[32 * 20];         // rad,|dx|,|dy|,|dz|, a[16]
  __shared__ float    dif[32 * 4];            // dx,dy,dz,rad
  __shared__ int      sl[32], dl[32];
  __shared__ float    p_lds[4][16];

  const int t = threadIdx.x;
  const int lane = t & 63;
  const int w = t >> 6;
  const int mtile = w >> 1;                   // 0/1
  const int nhalf = w & 1;                    // 0/1
  const int col = lane & 15;
  const int quad = lane >> 4;

  // stage W2 transposed as bf16
  for (int i = t; i < 128 * 128; i += 256) {
    int k = i >> 7, n = i & 127;
    W2Ts[n * 136 + k] = f2b(W2[i]);
  }
  // per-lane constant registers
  float wt0[20], wt1[20];
  #pragma unroll
  for (int k = 0; k < 20; ++k) {
    wt0[k] = W1[(256 + k) * 128 + 2 * lane];
    wt1[k] = W1[(256 + k) * 128 + 2 * lane + 1];
  }
  float b2reg[4], wvreg[4];
  #pragma unroll
  for (int nt = 0; nt < 4; ++nt) {
    int n = (nhalf * 4 + nt) * 16 + col;
    b2reg[nt] = b2[n];
    wvreg[nt] = Wv[n];
  }
  const float bav = (MODE == 0) ? ba_p[0] : 0.f;
  __syncthreads();

  const int ntiles = (E + 31) >> 5;
  for (int tile = blockIdx.x; tile < ntiles; tile += gridDim.x) {
    const int e0 = tile * 32;
    // ---- phase 0: stage per-edge scalars ----
    if (t < 32) {
      int eg = e0 + t;
      int s = 0, d = 0;
      if (eg < E) { s = src[eg]; d = dst[eg]; }
      sl[t] = s; dl[t] = d;
      float dx = coords[s*3+0] - coords[d*3+0];
      float dy = coords[s*3+1] - coords[d*3+1];
      float dz = coords[s*3+2] - coords[d*3+2];
      float rad = sqrtf(dx*dx + dy*dy + dz*dz);
      dif[t*4+0] = dx; dif[t*4+1] = dy; dif[t*4+2] = dz; dif[t*4+3] = rad;
      tails[t*20+0] = rad; tails[t*20+1] = fabsf(dx);
      tails[t*20+2] = fabsf(dy); tails[t*20+3] = fabsf(dz);
    }
    #pragma unroll
    for (int i = t; i < 512; i += 256) {
      int e = i >> 4, f = i & 15;
      int eg = e0 + e;
      tails[e*20 + 4 + f] = (eg < E) ? afeat[(size_t)eg * 16 + f] : 0.f;
    }
    __syncthreads();

    // ---- phase A: layer 1 assembly + silu -> mhl (each wave: 8 edges) ----
    {
      const int eb = w * 8;
      unsigned wa[8], wb[8];
      #pragma unroll
      for (int i = 0; i < 8; ++i) {
        wa[i] = Apart[(size_t)sl[eb + i] * HP + lane];
        wb[i] = Bpart[(size_t)dl[eb + i] * HP + lane];
      }
      #pragma unroll
      for (int i = 0; i < 8; ++i) {
        int e = eb + i;
        float t0 = blo(wa[i]) + blo(wb[i]);
        float t1 = bhi(wa[i]) + bhi(wb[i]);
        const float4* tp = (const float4*)&tails[e * 20];
        float4 v0 = tp[0], v1 = tp[1], v2 = tp[2], v3 = tp[3], v4 = tp[4];
        float tv[20] = {v0.x,v0.y,v0.z,v0.w, v1.x,v1.y,v1.z,v1.w,
                        v2.x,v2.y,v2.z,v2.w, v3.x,v3.y,v3.z,v3.w,
                        v4.x,v4.y,v4.z,v4.w};
        #pragma unroll
        for (int k = 0; k < 20; ++k) { t0 += tv[k] * wt0[k]; t1 += tv[k] * wt1[k]; }
        mhl[e * 68 + lane] = pack2(silu_f(t0), silu_f(t1));
      }
    }
    __syncthreads();

    // ---- phase B: layer 2 via MFMA ----
    float4v acc[4] = {{0,0,0,0},{0,0,0,0},{0,0,0,0},{0,0,0,0}};
    {
      const unsigned* abase = &mhl[(mtile * 16 + col) * 68 + quad * 4];
      #pragma unroll
      for (int ks = 0; ks < 4; ++ks) {
        short8 af = __builtin_bit_cast(short8, *(const uint4v*)(abase + ks * 16));
        #pragma unroll
        for (int nt = 0; nt < 4; ++nt) {
          const unsigned short* bp =
              &W2Ts[((nhalf * 4 + nt) * 16 + col) * 136 + ks * 32 + quad * 8];
          short8 bf = __builtin_bit_cast(short8, *(const uint4v*)bp);
          acc[nt] = __builtin_amdgcn_mfma_f32_16x16x32_bf16(af, bf, acc[nt], 0, 0, 0);
        }
      }
    }

    // ---- epilogue: bias + silu + head dot, cross-wave reduce, scatter ----
    float vv[4][4];
    float p[4] = {0.f, 0.f, 0.f, 0.f};
    #pragma unroll
    for (int nt = 0; nt < 4; ++nt)
      #pragma unroll
      for (int r = 0; r < 4; ++r) {
        float v = silu_f(acc[nt][r] + b2reg[nt]);
        vv[nt][r] = v;
        p[r] += v * wvreg[nt];
      }
    #pragma unroll
    for (int r = 0; r < 4; ++r) {
      #pragma unroll
      for (int off = 1; off < 16; off <<= 1) p[r] += __shfl_xor(p[r], off, 64);
    }
    if (col == 0) {
      #pragma unroll
      for (int r = 0; r < 4; ++r) p_lds[w][quad * 4 + r] = p[r];
    }
    __syncthreads();

    #pragma unroll
    for (int r = 0; r < 4; ++r) {
      const int le = quad * 4 + r;            // edge within Mtile
      const int ei = mtile * 16 + le;         // edge within 32-tile
      const int eg = e0 + ei;
      const float pfull = p_lds[w][le] + p_lds[w ^ 1][le];
      if (MODE == 0) {
        if (eg < E) {
          float att = 1.f / (1.f + __expf(-(pfull + bav)));
          int d = dl[ei];
          #pragma unroll
          for (int nt = 0; nt < 4; ++nt) {
            int n = (nhalf * 4 + nt) * 16 + col;
            unsafeAtomicAdd(&out_agg[(size_t)d * HH + n], att * vv[nt][r]);
          }
        }
      } else {
        if (nhalf == 0 && eg < E && col < 3) {
          float rad = dif[ei * 4 + 3];
          float fac = pfull / (rad + 1.f);
          unsafeAtomicAdd(&out_agg[(size_t)dl[ei] * 3 + col], fac * dif[ei * 4 + col]);
        }
      }
    }
    __syncthreads();                          // protect LDS reuse next tile
  }
}

// ---------- 3) node MLP layer 1: g = silu([h, h_agg] @ Wn1 + bn1), bf16-packed ----------
__global__ __launch_bounds__(256) void node_l1_kernel(
    const float* __restrict__ h, const float* __restrict__ h_agg,
    const float* __restrict__ Wn1, const float* __restrict__ bn1,
    unsigned* __restrict__ g, int N)
{
  __shared__ unsigned Wl[256 * HP];           // 64 KB
  int t = threadIdx.x;
  const float2* W2 = (const float2*)Wn1;
  for (int i = t; i < 256 * HP; i += 256) { float2 w = W2[i]; Wl[i] = pack2(w.x, w.y); }
  __syncthreads();

  int wid = blockIdx.x * 4 + (t >> 6);
  int nw  = gridDim.x * 4;
  int jp  = t & 63;
  for (int n = wid; n < N; n += nw) {
    float a0 = bn1[2*jp], a1 = bn1[2*jp + 1];
    const float4* hn = (const float4*)(h + (size_t)n * HH);
    const float4* gn = (const float4*)(h_agg + (size_t)n * HH);
    #pragma unroll 4
    for (int k4 = 0; k4 < 32; ++k4) {
      float4 hv = hn[k4];
      float xs[4] = {hv.x, hv.y, hv.z, hv.w};
      #pragma unroll
      for (int u = 0; u < 4; ++u) {
        unsigned w = Wl[(4*k4 + u) * HP + jp];
        a0 += xs[u] * blo(w); a1 += xs[u] * bhi(w);
      }
    }
    #pragma unroll 4
    for (int k4 = 0; k4 < 32; ++k4) {
      float4 hv = gn[k4];
      float xs[4] = {hv.x, hv.y, hv.z, hv.w};
      #pragma unroll
      for (int u = 0; u < 4; ++u) {
        unsigned w = Wl[(128 + 4*k4 + u) * HP + jp];
        a0 += xs[u] * blo(w); a1 += xs[u] * bhi(w);
      }
    }
    g[(size_t)n * HP + jp] = pack2(silu_f(a0), silu_f(a1));
  }
}

// ---------- 4) node MLP layer 2: h_out = h + g @ Wn2 + bn2 ----------
__global__ __launch_bounds__(256) void node_l2_kernel(
    const unsigned* __restrict__ g, const float* __restrict__ h,
    const float* __restrict__ Wn2, const float* __restrict__ bn2,
    float* __restrict__ hout, int N)
{
  __shared__ unsigned Wl[128 * HP];           // 32 KB
  int t = threadIdx.x;
  const float2* W2 = (const float2*)Wn2;
  for (int i = t; i < 128 * HP; i += 256) { float2 w = W2[i]; Wl[i] = pack2(w.x, w.y); }
  __syncthreads();

  int wid = blockIdx.x * 4 + (t >> 6);
  int nw  = gridDim.x * 4;
  int jp  = t & 63;
  for (int n = wid; n < N; n += nw) {
    float a0 = bn2[2*jp], a1 = bn2[2*jp + 1];
    const uint2* gn = (const uint2*)(g + (size_t)n * HP);
    #pragma unroll 4
    for (int k2 = 0; k2 < 32; ++k2) {
      uint2 gp = gn[k2];                      // 4 bf16 inputs
      float x0 = blo(gp.x), x1 = bhi(gp.x), x2 = blo(gp.y), x3 = bhi(gp.y);
      unsigned w0 = Wl[(4*k2    ) * HP + jp];
      unsigned w1 = Wl[(4*k2 + 1) * HP + jp];
      unsigned w2 = Wl[(4*k2 + 2) * HP + jp];
      unsigned w3 = Wl[(4*k2 + 3) * HP + jp];
      a0 += x0*blo(w0) + x1*blo(w1) + x2*blo(w2) + x3*blo(w3);
      a1 += x0*bhi(w0) + x1*bhi(w1) + x2*bhi(w2) + x3*bhi(w3);
    }
    float2 hv = ((const float2*)h)[(size_t)n * HP + jp];
    ((float2*)hout)[(size_t)n * HP + jp] = make_float2(hv.x + a0, hv.y + a1);
  }
}

// ---------- 5) coords_out = coords + x_agg ----------
__global__ void coords_out_kernel(const float* __restrict__ coords,
                                  const float* __restrict__ x_agg,
                                  float* __restrict__ out, int n3)
{
  int i = blockIdx.x * blockDim.x + threadIdx.x;
  if (i < n3) out[i] = coords[i] + x_agg[i];
}

extern "C" void kernel_launch(void* const* d_in, const int* in_sizes, int n_in,
                              void* d_out, int out_size, void* d_ws, size_t ws_size,
                              hipStream_t stream)
{
  const float* h      = (const float*)d_in[0];
  const float* coords = (const float*)d_in[1];
  const float* afeat  = (const float*)d_in[2];
  const int*   src    = (const int*)d_in[3];
  const int*   dst    = (const int*)d_in[4];
  const float* We1 = (const float*)d_in[5];
  const float* be1 = (const float*)d_in[6];
  const float* We2 = (const float*)d_in[7];
  const float* be2 = (const float*)d_in[8];
  const float* Wa  = (const float*)d_in[9];
  const float* ba  = (const float*)d_in[10];
  const float* Wn1 = (const float*)d_in[11];
  const float* bn1 = (const float*)d_in[12];
  const float* Wn2 = (const float*)d_in[13];
  const float* bn2 = (const float*)d_in[14];
  const float* Wc1 = (const float*)d_in[15];
  const float* bc1 = (const float*)d_in[16];
  const float* Wc2 = (const float*)d_in[17];
  const float* bc2 = (const float*)d_in[18];
  const float* Wc3 = (const float*)d_in[19];

  const int E = in_sizes[3];
  const int N = in_sizes[0] / HH;

  unsigned* A1 = (unsigned*)d_ws;
  unsigned* B1 = A1 + (size_t)N * HP;
  unsigned* Ac = B1 + (size_t)N * HP;
  unsigned* Bc = Ac + (size_t)N * HP;
  float* h_agg = (float*)(Bc + (size_t)N * HP);
  float* x_agg = h_agg + (size_t)N * HH;
  unsigned* gbuf = A1;                        // reuse after edge kernels finish

  hipMemsetAsync(h_agg, 0, ((size_t)N * HH + (size_t)N * 3) * sizeof(float), stream);

  precompute_kernel<<<512, 256, 0, stream>>>(h, We1, be1, A1, B1, N);
  precompute_kernel<<<512, 256, 0, stream>>>(h, Wc1, bc1, Ac, Bc, N);

  edge_kernel<0><<<768, 256, 0, stream>>>(A1, B1, We1, We2, be2, Wa, ba,
                                          src, dst, coords, afeat, h_agg, E);
  edge_kernel<1><<<768, 256, 0, stream>>>(Ac, Bc, Wc1, Wc2, bc2, Wc3, nullptr,
                                          src, dst, coords, afeat, x_agg, E);

  node_l1_kernel<<<512, 256, 0, stream>>>(h, h_agg, Wn1, bn1, gbuf, N);
  node_l2_kernel<<<1024, 256, 0, stream>>>(gbuf, h, Wn2, bn2, (float*)d_out, N);
  coords_out_kernel<<<(N * 3 + 255) / 256, 256, 0, stream>>>(
      coords, x_agg, (float*)d_out + (size_t)N * HH, N * 3);
}